// Round 2
// baseline (832.441 us; speedup 1.0000x reference)
//
#include <hip/hip_runtime.h>

#define N_IN    128
#define DD      256
#define KSEL    4096
#define NBATCH  8
#define NGROUP  16
#define NREP    4
#define CAND_CAP 65536
#define WBPG    98   // write-kernel blocks per group (98*1024 >= 100000)

// monotone map: float ordering -> unsigned ordering
__device__ __forceinline__ unsigned keyOf(float s){
    unsigned b = __float_as_uint(s);
    return (b & 0x80000000u) ? ~b : (b | 0x80000000u);
}

// ---------------------------------------------------------------------------
// Kernel 1: scores. One wave = 2 rows/iter (64 lanes x float4 = 256 floats).
// fp64 accumulate -> fp32 score -> radix key. Block 0 also zeroes the
// histogram + counters used by the later select pipeline.
// ---------------------------------------------------------------------------
__global__ __launch_bounds__(256) void scores_kernel(
        const float* __restrict__ x, const float* __restrict__ W_fr,
        const float* __restrict__ b_fr, unsigned* __restrict__ keys,
        unsigned* __restrict__ gHist, unsigned* __restrict__ gCandCnt,
        int N, int totalWaves)
{
    if (blockIdx.x == 0){
        for (int i = threadIdx.x; i < NGROUP*2048; i += 256) gHist[i] = 0u;
        if (threadIdx.x < NGROUP) gCandCnt[threadIdx.x] = 0u;
    }
    const int tid  = blockIdx.x * blockDim.x + threadIdx.x;
    const int wave = tid >> 6;
    const int lane = tid & 63;
    const int f = 4 * (lane & 31);
    const float w00 = W_fr[(f+0)*2+0], w01 = W_fr[(f+0)*2+1];
    const float w10 = W_fr[(f+1)*2+0], w11 = W_fr[(f+1)*2+1];
    const float w20 = W_fr[(f+2)*2+0], w21 = W_fr[(f+2)*2+1];
    const float w30 = W_fr[(f+3)*2+0], w31 = W_fr[(f+3)*2+1];
    const float bf0 = b_fr[0], bf1 = b_fr[1];
    const int half = N >> 1;
    for (int rp = wave; rp < half; rp += totalWaves){
        const int r0 = rp * 2;
        const float4 xv = *reinterpret_cast<const float4*>(x + (size_t)r0 * N_IN + 4*lane);
        double p0 = (double)xv.x*w00 + (double)xv.y*w10 + (double)xv.z*w20 + (double)xv.w*w30;
        double p1 = (double)xv.x*w01 + (double)xv.y*w11 + (double)xv.z*w21 + (double)xv.w*w31;
        #pragma unroll
        for (int off = 16; off; off >>= 1){
            p0 += __shfl_xor(p0, off, 32);
            p1 += __shfl_xor(p1, off, 32);
        }
        const int r = r0 + (lane >> 5);
        if ((lane & 31) == 0) keys[r]     = keyOf((float)(p0 + bf0));
        if ((lane & 31) == 1) keys[N + r] = keyOf((float)(p1 + bf1));
    }
}

// ---------------------------------------------------------------------------
// Kernel 2: parallel 11-bit (top) histogram. 16 groups x 8 chunks.
// ---------------------------------------------------------------------------
__global__ __launch_bounds__(1024) void histA_kernel(
        const unsigned* __restrict__ keys, unsigned* __restrict__ gHist,
        int N, int R)
{
    const int g = blockIdx.x >> 3, chunk = blockIdx.x & 7;
    const int b = g >> 1, v = g & 1;
    const unsigned* kk = keys + (size_t)v * N + (size_t)b * R;
    const int tid = threadIdx.x;
    __shared__ unsigned lh[NREP][2048];
    for (int i = tid; i < NREP*2048; i += 1024) (&lh[0][0])[i] = 0u;
    __syncthreads();
    const int span = R >> 3;                  // 12500
    const int lo = chunk * span, hi = lo + span;
    const int rep = (tid >> 6) & (NREP-1);
    for (int i = lo + tid; i < hi; i += 1024)
        atomicAdd(&lh[rep][kk[i] >> 21], 1u);
    __syncthreads();
    unsigned* gh = gHist + g * 2048;
    for (int bin = tid; bin < 2048; bin += 1024){
        unsigned s = 0;
        #pragma unroll
        for (int rp = 0; rp < NREP; ++rp) s += lh[rp][bin];
        if (s) atomicAdd(&gh[bin], s);
    }
}

// ---------------------------------------------------------------------------
// Kernel 3: per-group threshold from the 11-bit histogram -> B1, kneed1.
// ---------------------------------------------------------------------------
__global__ __launch_bounds__(256) void threshA_kernel(
        const unsigned* __restrict__ gHist, unsigned* __restrict__ gParams)
{
    const int g = blockIdx.x, tid = threadIdx.x;
    __shared__ unsigned lh[2048];
    __shared__ unsigned coarse[32];
    const unsigned* gh = gHist + g * 2048;
    for (int i = tid; i < 2048; i += 256) lh[i] = gh[i];
    __syncthreads();
    if (tid < 32){ unsigned s = 0; for (int j = 0; j < 64; ++j) s += lh[tid*64+j]; coarse[tid] = s; }
    __syncthreads();
    if (tid == 0){
        unsigned kneed = KSEL, cum = 0; int cb = 31;
        for (; cb > 0; --cb){ if (cum + coarse[cb] >= kneed) break; cum += coarse[cb]; }
        int bin = cb*64 + 63;
        for (; bin > cb*64; --bin){ if (cum + lh[bin] >= kneed) break; cum += lh[bin]; }
        gParams[g*8+0] = (unsigned)bin;
        gParams[g*8+1] = kneed - cum;
    }
}

// ---------------------------------------------------------------------------
// Kernel 4: collect candidate indices (top bucket == B1). 16 groups x 8 chunks,
// wave-aggregated atomic append (order-free).
// ---------------------------------------------------------------------------
__global__ __launch_bounds__(1024) void collect_kernel(
        const unsigned* __restrict__ keys, const unsigned* __restrict__ gParams,
        unsigned* __restrict__ gCandCnt, int* __restrict__ cand,
        int N, int R)
{
    const int g = blockIdx.x >> 3, chunk = blockIdx.x & 7;
    const int b = g >> 1, v = g & 1;
    const unsigned* kk = keys + (size_t)v * N + (size_t)b * R;
    const unsigned B1 = gParams[g*8+0];
    int* cd = cand + (size_t)g * CAND_CAP;
    const int tid = threadIdx.x, lane = tid & 63;
    const int span = R >> 3;
    const int lo = chunk * span, hi = lo + span;
    for (int i0 = lo; i0 < hi; i0 += 1024){
        const int i = i0 + tid;
        const bool pred = (i < hi) && ((kk[i] >> 21) == B1);
        unsigned long long m = __ballot(pred);
        const unsigned cnt = (unsigned)__popcll(m);
        unsigned base = 0;
        if (lane == 0 && cnt) base = atomicAdd(&gCandCnt[g], cnt);
        base = (unsigned)__shfl((int)base, 0);
        if (pred){
            const unsigned p = base + (unsigned)__popcll(m & ((1ULL << lane) - 1ULL));
            if (p < CAND_CAP) cd[p] = i;
        }
    }
}

// ---------------------------------------------------------------------------
// Kernel 5: one block per group. Refine candidates over low 21 bits -> exact
// utar + take_eq, then T = take_eq-th smallest index among key==utar
// (so the stable tie-break becomes the predicate idx <= T). Zeroes gListCnt.
// ---------------------------------------------------------------------------
__global__ __launch_bounds__(1024) void select2_kernel(
        const unsigned* __restrict__ keys, const int* __restrict__ cand,
        const unsigned* __restrict__ gCandCnt, unsigned* __restrict__ gParams,
        unsigned* __restrict__ gListCnt, int N, int R)
{
    const int g = blockIdx.x, b = g >> 1, v = g & 1;
    const unsigned* kk = keys + (size_t)v * N + (size_t)b * R;
    const int* cd = cand + (size_t)g * CAND_CAP;
    const int tid = threadIdx.x;
    const int nc = (int)min(gCandCnt[g], (unsigned)CAND_CAP);
    const unsigned B1 = gParams[g*8+0];
    const unsigned kneed1 = gParams[g*8+1];

    __shared__ unsigned h[2048];
    __shared__ unsigned coarse[32];
    __shared__ unsigned sres[2];

    // ---- phase B: bits 20..10 (descending) ----
    for (int i = tid; i < 2048; i += 1024) h[i] = 0u;
    __syncthreads();
    for (int i = tid; i < nc; i += 1024)
        atomicAdd(&h[(kk[cd[i]] >> 10) & 0x7FFu], 1u);
    __syncthreads();
    if (tid < 32){ unsigned s = 0; for (int j = 0; j < 64; ++j) s += h[tid*64+j]; coarse[tid] = s; }
    __syncthreads();
    if (tid == 0){
        unsigned kneed = kneed1, cum = 0; int cb = 31;
        for (; cb > 0; --cb){ if (cum + coarse[cb] >= kneed) break; cum += coarse[cb]; }
        int bin = cb*64 + 63;
        for (; bin > cb*64; --bin){ if (cum + h[bin] >= kneed) break; cum += h[bin]; }
        sres[0] = (unsigned)bin; sres[1] = kneed - cum;
    }
    __syncthreads();
    const unsigned B2 = sres[0], kneed2 = sres[1];
    const unsigned top22 = (B1 << 11) | B2;
    __syncthreads();

    // ---- phase C: low 10 bits (descending) ----
    for (int i = tid; i < 1024; i += 1024) h[i] = 0u;
    __syncthreads();
    for (int i = tid; i < nc; i += 1024){
        const unsigned u = kk[cd[i]];
        if ((u >> 10) == top22) atomicAdd(&h[u & 0x3FFu], 1u);
    }
    __syncthreads();
    if (tid < 32){ unsigned s = 0; for (int j = 0; j < 32; ++j) s += h[tid*32+j]; coarse[tid] = s; }
    __syncthreads();
    if (tid == 0){
        unsigned kneed = kneed2, cum = 0; int cb = 31;
        for (; cb > 0; --cb){ if (cum + coarse[cb] >= kneed) break; cum += coarse[cb]; }
        int bin = cb*32 + 31;
        for (; bin > cb*32; --bin){ if (cum + h[bin] >= kneed) break; cum += h[bin]; }
        sres[0] = (unsigned)bin; sres[1] = kneed - cum;
    }
    __syncthreads();
    const unsigned B3 = sres[0], take_eq = sres[1];
    const unsigned utar = (B1 << 21) | (B2 << 10) | B3;
    __syncthreads();

    // ---- phase T1: hist of idx>>7 among eq (ascending) ----
    for (int i = tid; i < 1024; i += 1024) h[i] = 0u;
    __syncthreads();
    for (int i = tid; i < nc; i += 1024){
        const int ix = cd[i];
        if (kk[ix] == utar) atomicAdd(&h[ix >> 7], 1u);
    }
    __syncthreads();
    if (tid < 32){ unsigned s = 0; for (int j = 0; j < 32; ++j) s += h[tid*32+j]; coarse[tid] = s; }
    __syncthreads();
    if (tid == 0){
        unsigned need = take_eq, cum = 0; int cb = 0;
        for (; cb < 31; ++cb){ if (cum + coarse[cb] >= need) break; cum += coarse[cb]; }
        int bin = cb*32;
        for (; bin < cb*32+31; ++bin){ if (cum + h[bin] >= need) break; cum += h[bin]; }
        sres[0] = (unsigned)bin; sres[1] = need - cum;
    }
    __syncthreads();
    const unsigned cb7 = sres[0], rem = sres[1];
    __syncthreads();

    // ---- phase T2: low 7 index bits (ascending) ----
    for (int i = tid; i < 128; i += 1024) h[i] = 0u;
    __syncthreads();
    for (int i = tid; i < nc; i += 1024){
        const int ix = cd[i];
        if (kk[ix] == utar && (unsigned)(ix >> 7) == cb7) atomicAdd(&h[ix & 127], 1u);
    }
    __syncthreads();
    if (tid == 0){
        unsigned need = rem, cum = 0; int p = 0;
        for (; p < 127; ++p){ if (cum + h[p] >= need) break; cum += h[p]; }
        gParams[g*8+2] = utar;
        gParams[g*8+3] = cb7*128 + (unsigned)p;   // T
        gListCnt[g] = 0u;
    }
}

// ---------------------------------------------------------------------------
// Kernel 6: parallel mask + (unordered) compact list.
// sel = u > utar || (u == utar && idx <= T).
// ---------------------------------------------------------------------------
__global__ __launch_bounds__(1024) void write_kernel(
        const unsigned* __restrict__ keys, const unsigned* __restrict__ gParams,
        unsigned char* __restrict__ mask, int* __restrict__ lists,
        unsigned* __restrict__ gListCnt, int N, int R)
{
    const int g = blockIdx.x / WBPG, c = blockIdx.x % WBPG;
    const int b = g >> 1, v = g & 1;
    const unsigned* kk = keys + (size_t)v * N + (size_t)b * R;
    unsigned char* mk = mask + (size_t)v * N + (size_t)b * R;
    int* lst = lists + g * KSEL;
    const unsigned utar = gParams[g*8+2];
    const int T = (int)gParams[g*8+3];
    const int tid = threadIdx.x, lane = tid & 63;
    const int i = c * 1024 + tid;
    const unsigned u = (i < R) ? kk[i] : 0u;
    const bool sel = (i < R) && (u > utar || (u == utar && i <= T));
    unsigned long long m = __ballot(sel);
    const unsigned cnt = (unsigned)__popcll(m);
    unsigned base = 0;
    if (lane == 0 && cnt) base = atomicAdd(&gListCnt[g], cnt);
    base = (unsigned)__shfl((int)base, 0);
    if (i < R){
        mk[i] = sel ? (unsigned char)1 : (unsigned char)0;
        if (sel) lst[base + (unsigned)__popcll(m & ((1ULL << lane) - 1ULL))] = i;
    }
}

// ---------------------------------------------------------------------------
// Kernel 7: gather selected rows -> deterministic-enough fp64 partial sums.
// ---------------------------------------------------------------------------
__global__ __launch_bounds__(256) void virt_partial_kernel(
        const float* __restrict__ x, const int* __restrict__ lists,
        double* __restrict__ part, int R)
{
    const int g = blockIdx.x >> 6;
    const int m = blockIdx.x & 63;
    const int b = g >> 1;
    const int tid = threadIdx.x, wave = tid >> 6, lane = tid & 63;
    const int* lst = lists + g * KSEL + m * 64;
    int idxs[16];
    #pragma unroll
    for (int e = 0; e < 16; ++e) idxs[e] = lst[e*4 + wave];
    double a0 = 0.0, a1 = 0.0;
    #pragma unroll
    for (int e = 0; e < 16; ++e){
        const float2 xv = *reinterpret_cast<const float2*>(
            x + ((size_t)b * R + idxs[e]) * N_IN + 2*lane);
        a0 += xv.x; a1 += xv.y;
    }
    __shared__ double pp[4][128];
    pp[wave][2*lane]   = a0;
    pp[wave][2*lane+1] = a1;
    __syncthreads();
    if (tid < 128){
        double s = pp[0][tid] + pp[1][tid] + pp[2][tid] + pp[3][tid];
        part[(size_t)(g*64 + m) * N_IN + tid] = s;
    }
}

// ---------------------------------------------------------------------------
// Kernel 8: reduce partials -> virt (/K), then the tiny 2-layer MLP.
// ---------------------------------------------------------------------------
__global__ __launch_bounds__(256) void mlp_kernel(
        const double* __restrict__ part,
        const float* __restrict__ W1, const float* __restrict__ b1,
        const float* __restrict__ W2, const float* __restrict__ b2,
        float* __restrict__ upd)
{
    const int b = blockIdx.x, j = threadIdx.x;
    __shared__ float inv[DD];
    __shared__ float h1[DD];
    {
        const int g = b*2 + (j >> 7);
        const int f = j & 127;
        const double* p = part + (size_t)g * 64 * N_IN + f;
        double s = 0.0;
        for (int m = 0; m < 64; ++m) s += p[(size_t)m * N_IN];
        inv[j] = (float)(s / (double)KSEL);
    }
    __syncthreads();
    double acc = 0.0;
    for (int i = 0; i < DD; ++i) acc += (double)inv[i] * (double)W1[i*DD + j];
    h1[j] = fmaxf((float)(acc + (double)b1[j]), 0.0f);
    __syncthreads();
    acc = 0.0;
    for (int i = 0; i < DD; ++i) acc += (double)h1[i] * (double)W2[i*DD + j];
    upd[b*DD + j] = (float)(acc + (double)b2[j]);
}

// ---------------------------------------------------------------------------
// Kernel 9: final blend.
// ---------------------------------------------------------------------------
__global__ __launch_bounds__(256) void final_kernel(
        const float* __restrict__ x,
        const unsigned char* __restrict__ mask,
        const float* __restrict__ upd,
        float* __restrict__ out, int N, int R)
{
    const int nvec = N * (N_IN / 4);
    const int stride = gridDim.x * blockDim.x;
    for (int idx = blockIdx.x * blockDim.x + threadIdx.x; idx < nvec; idx += stride){
        const int row = idx >> 5;
        const int c = (idx & 31) * 4;
        float4 o = *reinterpret_cast<const float4*>(x + (size_t)row * N_IN + c);
        const int b = row / R;
        const unsigned char m0 = mask[row];
        const unsigned char m1 = mask[(size_t)N + row];
        if (m0){
            const float4 u0 = *reinterpret_cast<const float4*>(upd + b*DD + c);
            o.x = (o.x + u0.x)*0.5f; o.y = (o.y + u0.y)*0.5f;
            o.z = (o.z + u0.z)*0.5f; o.w = (o.w + u0.w)*0.5f;
        }
        if (m1){
            const float4 u1 = *reinterpret_cast<const float4*>(upd + b*DD + 128 + c);
            o.x = (o.x + u1.x)*0.5f; o.y = (o.y + u1.y)*0.5f;
            o.z = (o.z + u1.z)*0.5f; o.w = (o.w + u1.w)*0.5f;
        }
        *reinterpret_cast<float4*>(out + (size_t)row * N_IN + c) = o;
    }
}

extern "C" void kernel_launch(void* const* d_in, const int* in_sizes, int n_in_cnt,
                              void* d_out, int out_size, void* d_ws, size_t ws_size,
                              hipStream_t stream)
{
    const float* x    = (const float*)d_in[0];
    const float* W_fr = (const float*)d_in[1];
    const float* b_fr = (const float*)d_in[2];
    const float* W1   = (const float*)d_in[3];
    const float* b1   = (const float*)d_in[4];
    const float* W2   = (const float*)d_in[5];
    const float* b2   = (const float*)d_in[6];
    float* out = (float*)d_out;

    const int N = in_sizes[0] / N_IN;   // 800000
    const int R = N / NBATCH;           // 100000

    char* ws = (char*)d_ws;
    size_t off = 0;
    auto alloc = [&](size_t bytes) -> void* {
        void* p = ws + off;
        off = (off + bytes + 255) & ~(size_t)255;
        return p;
    };
    unsigned char* mask = (unsigned char*)alloc((size_t)2 * N);
    int*      lists    = (int*)     alloc((size_t)NGROUP * KSEL * 4);
    double*   part     = (double*)  alloc((size_t)NGROUP * 64 * N_IN * 8);
    float*    upd      = (float*)   alloc((size_t)NBATCH * DD * 4);
    unsigned* gHist    = (unsigned*)alloc((size_t)NGROUP * 2048 * 4);
    unsigned* gParams  = (unsigned*)alloc((size_t)NGROUP * 8 * 4);
    unsigned* gCandCnt = (unsigned*)alloc((size_t)NGROUP * 4);
    unsigned* gListCnt = (unsigned*)alloc((size_t)NGROUP * 4);

    // big buffers with d_out-tail fallback (all consumers precede final_kernel)
    const size_t outBytes  = (size_t)out_size * 4;
    char* tail = (char*)d_out + outBytes;
    auto tail_alloc = [&](size_t bytes) -> void* {
        tail -= bytes;
        tail = (char*)((size_t)tail & ~(size_t)255);
        return tail;
    };
    unsigned* keys;
    const size_t keyBytes = (size_t)2 * N * 4;
    if (off + keyBytes <= ws_size) keys = (unsigned*)alloc(keyBytes);
    else                           keys = (unsigned*)tail_alloc(keyBytes);
    int* cand;
    const size_t candBytes = (size_t)NGROUP * CAND_CAP * 4;
    if (off + candBytes <= ws_size) cand = (int*)alloc(candBytes);
    else                            cand = (int*)tail_alloc(candBytes);

    const int totalWaves = 2048 * 256 / 64;
    scores_kernel<<<dim3(2048), dim3(256), 0, stream>>>(x, W_fr, b_fr, keys, gHist, gCandCnt, N, totalWaves);
    histA_kernel<<<dim3(NGROUP*8), dim3(1024), 0, stream>>>(keys, gHist, N, R);
    threshA_kernel<<<dim3(NGROUP), dim3(256), 0, stream>>>(gHist, gParams);
    collect_kernel<<<dim3(NGROUP*8), dim3(1024), 0, stream>>>(keys, gParams, gCandCnt, cand, N, R);
    select2_kernel<<<dim3(NGROUP), dim3(1024), 0, stream>>>(keys, cand, gCandCnt, gParams, gListCnt, N, R);
    write_kernel<<<dim3(NGROUP*WBPG), dim3(1024), 0, stream>>>(keys, gParams, mask, lists, gListCnt, N, R);
    virt_partial_kernel<<<dim3(NGROUP*64), dim3(256), 0, stream>>>(x, lists, part, R);
    mlp_kernel<<<dim3(NBATCH), dim3(DD), 0, stream>>>(part, W1, b1, W2, b2, upd);
    final_kernel<<<dim3(2048), dim3(256), 0, stream>>>(x, mask, upd, out, N, R);
}

// Round 3
// 389.745 us; speedup vs baseline: 2.1359x; 2.1359x over previous
//
#include <hip/hip_runtime.h>

#define N_IN    128
#define DD      256
#define KSEL    4096
#define NBATCH  8
#define NGROUP  16
#define CHUNKS  16          // hist/collect chunks per group
#define SUBCAP  4096        // candidate sub-range per (group,chunk)
#define CAND_CAP (CHUNKS*SUBCAP)
#define WCH     13          // write-kernel blocks per group (13*8192 >= 100000)
#define HREP    4
#define HSTRIDE 2056        // 2056%32==8 -> replicas land in distinct banks

// monotone map: float ordering -> unsigned ordering
__device__ __forceinline__ unsigned keyOf(float s){
    unsigned b = __float_as_uint(s);
    return (b & 0x80000000u) ? ~b : (b | 0x80000000u);
}

// ---------------------------------------------------------------------------
// Kernel 1: scores. One wave = 2 rows/iter (64 lanes x float4 = 256 floats).
// fp64 accumulate -> fp32 score -> radix key.
// ---------------------------------------------------------------------------
__global__ __launch_bounds__(256) void scores_kernel(
        const float* __restrict__ x, const float* __restrict__ W_fr,
        const float* __restrict__ b_fr, unsigned* __restrict__ keys,
        int N, int totalWaves)
{
    const int tid  = blockIdx.x * blockDim.x + threadIdx.x;
    const int wave = tid >> 6;
    const int lane = tid & 63;
    const int f = 4 * (lane & 31);
    const float w00 = W_fr[(f+0)*2+0], w01 = W_fr[(f+0)*2+1];
    const float w10 = W_fr[(f+1)*2+0], w11 = W_fr[(f+1)*2+1];
    const float w20 = W_fr[(f+2)*2+0], w21 = W_fr[(f+2)*2+1];
    const float w30 = W_fr[(f+3)*2+0], w31 = W_fr[(f+3)*2+1];
    const float bf0 = b_fr[0], bf1 = b_fr[1];
    const int half = N >> 1;
    for (int rp = wave; rp < half; rp += totalWaves){
        const int r0 = rp * 2;
        const float4 xv = *reinterpret_cast<const float4*>(x + (size_t)r0 * N_IN + 4*lane);
        double p0 = (double)xv.x*w00 + (double)xv.y*w10 + (double)xv.z*w20 + (double)xv.w*w30;
        double p1 = (double)xv.x*w01 + (double)xv.y*w11 + (double)xv.z*w21 + (double)xv.w*w31;
        #pragma unroll
        for (int off = 16; off; off >>= 1){
            p0 += __shfl_xor(p0, off, 32);
            p1 += __shfl_xor(p1, off, 32);
        }
        const int r = r0 + (lane >> 5);
        if ((lane & 31) == 0) keys[r]     = keyOf((float)(p0 + bf0));
        if ((lane & 31) == 1) keys[N + r] = keyOf((float)(p1 + bf1));
    }
}

// ---------------------------------------------------------------------------
// Kernel 2: 11-bit top histogram, per (group,chunk) partial hist, PLAIN stores.
// ---------------------------------------------------------------------------
__global__ __launch_bounds__(1024) void histA_kernel(
        const unsigned* __restrict__ keys, unsigned* __restrict__ gHist,
        int N, int R)
{
    const int g = blockIdx.x >> 4, ch = blockIdx.x & 15;
    const int b = g >> 1, v = g & 1;
    const unsigned* kk = keys + (size_t)v * N + (size_t)b * R;
    const int tid = threadIdx.x, lane = tid & 63;
    __shared__ unsigned lh[HREP*HSTRIDE];
    for (int i = tid; i < HREP*HSTRIDE; i += 1024) lh[i] = 0u;
    __syncthreads();
    const int span = R / CHUNKS;                 // 6250
    const int lo = ch * span, hi = lo + span;
    const int rep = lane & (HREP-1);
    for (int i = lo + tid; i < hi; i += 1024)
        atomicAdd(&lh[rep*HSTRIDE + (kk[i] >> 21)], 1u);
    __syncthreads();
    unsigned* gh = gHist + (size_t)(g*CHUNKS + ch) * 2048;
    for (int bin = tid; bin < 2048; bin += 1024){
        unsigned s = 0;
        #pragma unroll
        for (int rp = 0; rp < HREP; ++rp) s += lh[rp*HSTRIDE + bin];
        gh[bin] = s;
    }
}

// ---------------------------------------------------------------------------
// Kernel 3: per-group threshold: sum chunk hists -> B1, kneed1.
// ---------------------------------------------------------------------------
__global__ __launch_bounds__(256) void threshA_kernel(
        const unsigned* __restrict__ gHist, unsigned* __restrict__ gParams)
{
    const int g = blockIdx.x, tid = threadIdx.x;
    __shared__ unsigned lh[2048];
    __shared__ unsigned coarse[32];
    const unsigned* gh = gHist + (size_t)g * CHUNKS * 2048;
    for (int bin = tid; bin < 2048; bin += 256){
        unsigned s = 0;
        #pragma unroll
        for (int ch = 0; ch < CHUNKS; ++ch) s += gh[ch*2048 + bin];
        lh[bin] = s;
    }
    __syncthreads();
    if (tid < 32){ unsigned s = 0; for (int j = 0; j < 64; ++j) s += lh[tid*64+j]; coarse[tid] = s; }
    __syncthreads();
    if (tid == 0){
        unsigned kneed = KSEL, cum = 0; int cb = 31;
        for (; cb > 0; --cb){ if (cum + coarse[cb] >= kneed) break; cum += coarse[cb]; }
        int bin = cb*64 + 63;
        for (; bin > cb*64; --bin){ if (cum + lh[bin] >= kneed) break; cum += lh[bin]; }
        gParams[g*8+0] = (unsigned)bin;
        gParams[g*8+1] = kneed - cum;
    }
}

// ---------------------------------------------------------------------------
// Kernel 4: collect boundary-bucket candidates into per-chunk sub-ranges.
// LDS block scan, ZERO global atomics; count via plain store.
// ---------------------------------------------------------------------------
__global__ __launch_bounds__(1024) void collect_kernel(
        const unsigned* __restrict__ keys, const unsigned* __restrict__ gParams,
        unsigned* __restrict__ gCandCnt, int* __restrict__ cand,
        int N, int R)
{
    const int g = blockIdx.x >> 4, ch = blockIdx.x & 15;
    const int b = g >> 1, v = g & 1;
    const unsigned* kk = keys + (size_t)v * N + (size_t)b * R;
    const unsigned B1 = gParams[g*8+0];
    int* cd = cand + (size_t)g * CAND_CAP + ch * SUBCAP;
    const int tid = threadIdx.x, wave = tid >> 6, lane = tid & 63;
    const int span = R / CHUNKS;
    const int lo = ch * span, hi = lo + span;
    __shared__ unsigned waveCnt[16];
    __shared__ unsigned sLoc;
    if (tid == 0) sLoc = 0u;
    __syncthreads();
    for (int i0 = lo; i0 < hi; i0 += 1024){
        const int i = i0 + tid;
        const bool pred = (i < hi) && ((kk[i] >> 21) == B1);
        unsigned long long m = __ballot(pred);
        if (lane == 0) waveCnt[wave] = (unsigned)__popcll(m);
        __syncthreads();
        unsigned pre = sLoc, tot = 0;
        #pragma unroll
        for (int w = 0; w < 16; ++w){ unsigned c = waveCnt[w]; if (w < wave) pre += c; tot += c; }
        if (pred){
            const unsigned p = pre + (unsigned)__popcll(m & ((1ULL << lane) - 1ULL));
            if (p < (unsigned)SUBCAP) cd[p] = i;
        }
        __syncthreads();
        if (tid == 0) sLoc += tot;
    }
    __syncthreads();
    if (tid == 0) gCandCnt[g*CHUNKS + ch] = min(sLoc, (unsigned)SUBCAP);
}

// ---------------------------------------------------------------------------
// Kernel 5: one block per group. Refine candidates (low 21 bits) -> exact utar
// + take_eq, then T = take_eq-th smallest tied index. Zeroes gListCnt.
// ---------------------------------------------------------------------------
__global__ __launch_bounds__(1024) void select2_kernel(
        const unsigned* __restrict__ keys, const int* __restrict__ cand,
        const unsigned* __restrict__ gCandCnt, unsigned* __restrict__ gParams,
        unsigned* __restrict__ gListCnt, int N, int R)
{
    const int g = blockIdx.x, b = g >> 1, v = g & 1;
    const unsigned* kk = keys + (size_t)v * N + (size_t)b * R;
    const int* cd0 = cand + (size_t)g * CAND_CAP;
    const int tid = threadIdx.x;
    const unsigned B1 = gParams[g*8+0];
    const unsigned kneed1 = gParams[g*8+1];
    __shared__ unsigned ncc[CHUNKS];
    if (tid < CHUNKS) ncc[tid] = gCandCnt[g*CHUNKS + tid];
    __shared__ unsigned h[2048];
    __shared__ unsigned coarse[32];
    __shared__ unsigned sres[2];

    // ---- phase B: bits 20..10 (descending) ----
    for (int i = tid; i < 2048; i += 1024) h[i] = 0u;
    __syncthreads();
    for (int ch = 0; ch < CHUNKS; ++ch){
        const int n = (int)ncc[ch]; const int* cd = cd0 + ch*SUBCAP;
        for (int i = tid; i < n; i += 1024)
            atomicAdd(&h[(kk[cd[i]] >> 10) & 0x7FFu], 1u);
    }
    __syncthreads();
    if (tid < 32){ unsigned s = 0; for (int j = 0; j < 64; ++j) s += h[tid*64+j]; coarse[tid] = s; }
    __syncthreads();
    if (tid == 0){
        unsigned kneed = kneed1, cum = 0; int cb = 31;
        for (; cb > 0; --cb){ if (cum + coarse[cb] >= kneed) break; cum += coarse[cb]; }
        int bin = cb*64 + 63;
        for (; bin > cb*64; --bin){ if (cum + h[bin] >= kneed) break; cum += h[bin]; }
        sres[0] = (unsigned)bin; sres[1] = kneed - cum;
    }
    __syncthreads();
    const unsigned B2 = sres[0], kneed2 = sres[1];
    const unsigned top22 = (B1 << 11) | B2;
    __syncthreads();

    // ---- phase C: low 10 bits (descending) ----
    for (int i = tid; i < 1024; i += 1024) h[i] = 0u;
    __syncthreads();
    for (int ch = 0; ch < CHUNKS; ++ch){
        const int n = (int)ncc[ch]; const int* cd = cd0 + ch*SUBCAP;
        for (int i = tid; i < n; i += 1024){
            const unsigned u = kk[cd[i]];
            if ((u >> 10) == top22) atomicAdd(&h[u & 0x3FFu], 1u);
        }
    }
    __syncthreads();
    if (tid < 32){ unsigned s = 0; for (int j = 0; j < 32; ++j) s += h[tid*32+j]; coarse[tid] = s; }
    __syncthreads();
    if (tid == 0){
        unsigned kneed = kneed2, cum = 0; int cb = 31;
        for (; cb > 0; --cb){ if (cum + coarse[cb] >= kneed) break; cum += coarse[cb]; }
        int bin = cb*32 + 31;
        for (; bin > cb*32; --bin){ if (cum + h[bin] >= kneed) break; cum += h[bin]; }
        sres[0] = (unsigned)bin; sres[1] = kneed - cum;
    }
    __syncthreads();
    const unsigned B3 = sres[0], take_eq = sres[1];
    const unsigned utar = (B1 << 21) | (B2 << 10) | B3;
    __syncthreads();

    // ---- phase T1: hist of idx>>7 among ties (ascending) ----
    for (int i = tid; i < 1024; i += 1024) h[i] = 0u;
    __syncthreads();
    for (int ch = 0; ch < CHUNKS; ++ch){
        const int n = (int)ncc[ch]; const int* cd = cd0 + ch*SUBCAP;
        for (int i = tid; i < n; i += 1024){
            const int ix = cd[i];
            if (kk[ix] == utar) atomicAdd(&h[ix >> 7], 1u);
        }
    }
    __syncthreads();
    if (tid < 32){ unsigned s = 0; for (int j = 0; j < 32; ++j) s += h[tid*32+j]; coarse[tid] = s; }
    __syncthreads();
    if (tid == 0){
        unsigned need = take_eq, cum = 0; int cb = 0;
        for (; cb < 31; ++cb){ if (cum + coarse[cb] >= need) break; cum += coarse[cb]; }
        int bin = cb*32;
        for (; bin < cb*32+31; ++bin){ if (cum + h[bin] >= need) break; cum += h[bin]; }
        sres[0] = (unsigned)bin; sres[1] = need - cum;
    }
    __syncthreads();
    const unsigned cb7 = sres[0], rem = sres[1];
    __syncthreads();

    // ---- phase T2: low 7 index bits (ascending) ----
    for (int i = tid; i < 128; i += 1024) h[i] = 0u;
    __syncthreads();
    for (int ch = 0; ch < CHUNKS; ++ch){
        const int n = (int)ncc[ch]; const int* cd = cd0 + ch*SUBCAP;
        for (int i = tid; i < n; i += 1024){
            const int ix = cd[i];
            if (kk[ix] == utar && (unsigned)(ix >> 7) == cb7) atomicAdd(&h[ix & 127], 1u);
        }
    }
    __syncthreads();
    if (tid == 0){
        unsigned need = rem, cum = 0; int p = 0;
        for (; p < 127; ++p){ if (cum + h[p] >= need) break; cum += h[p]; }
        gParams[g*8+2] = utar;
        gParams[g*8+3] = cb7*128 + (unsigned)p;   // T
        gListCnt[g*64] = 0u;
    }
}

// ---------------------------------------------------------------------------
// Kernel 6: mask + compact list. 8192 rows/block, ONE global atomic per block
// (padded per-group cache lines).
// ---------------------------------------------------------------------------
__global__ __launch_bounds__(1024) void write_kernel(
        const unsigned* __restrict__ keys, const unsigned* __restrict__ gParams,
        unsigned char* __restrict__ mask, int* __restrict__ lists,
        unsigned* __restrict__ gListCnt, int N, int R)
{
    const int g = blockIdx.x / WCH, c = blockIdx.x % WCH;
    const int b = g >> 1, v = g & 1;
    const unsigned* kk = keys + (size_t)v * N + (size_t)b * R;
    unsigned char* mk = mask + (size_t)v * N + (size_t)b * R;
    int* lst = lists + g * KSEL;
    const unsigned utar = gParams[g*8+2];
    const int T = (int)gParams[g*8+3];
    const int tid = threadIdx.x, wave = tid >> 6, lane = tid & 63;
    const int i0 = c * 8192;

    bool pr[8];
    #pragma unroll
    for (int j = 0; j < 8; ++j){
        const int i = i0 + j*1024 + tid;
        const unsigned u = (i < R) ? kk[i] : 0u;
        pr[j] = (i < R) && (u > utar || (u == utar && i <= T));
        if (i < R) mk[i] = pr[j] ? (unsigned char)1 : (unsigned char)0;
    }
    __shared__ unsigned wc[8][16];
    __shared__ unsigned ec[8][16];
    __shared__ unsigned sBase;
    #pragma unroll
    for (int j = 0; j < 8; ++j){
        unsigned long long m = __ballot(pr[j]);
        if (lane == 0) wc[j][wave] = (unsigned)__popcll(m);
    }
    __syncthreads();
    if (tid == 0){
        unsigned run = 0;
        for (int j = 0; j < 8; ++j)
            for (int w = 0; w < 16; ++w){ ec[j][w] = run; run += wc[j][w]; }
        sBase = run ? atomicAdd(&gListCnt[g*64], run) : 0u;
    }
    __syncthreads();
    const unsigned base = sBase;
    #pragma unroll
    for (int j = 0; j < 8; ++j){
        unsigned long long m = __ballot(pr[j]);
        if (pr[j])
            lst[base + ec[j][wave] + (unsigned)__popcll(m & ((1ULL << lane) - 1ULL))] = i0 + j*1024 + tid;
    }
}

// ---------------------------------------------------------------------------
// Kernel 7: gather selected rows -> fp64 partial sums.
// ---------------------------------------------------------------------------
__global__ __launch_bounds__(256) void virt_partial_kernel(
        const float* __restrict__ x, const int* __restrict__ lists,
        double* __restrict__ part, int R)
{
    const int g = blockIdx.x >> 6;
    const int m = blockIdx.x & 63;
    const int b = g >> 1;
    const int tid = threadIdx.x, wave = tid >> 6, lane = tid & 63;
    const int* lst = lists + g * KSEL + m * 64;
    int idxs[16];
    #pragma unroll
    for (int e = 0; e < 16; ++e) idxs[e] = lst[e*4 + wave];
    double a0 = 0.0, a1 = 0.0;
    #pragma unroll
    for (int e = 0; e < 16; ++e){
        const float2 xv = *reinterpret_cast<const float2*>(
            x + ((size_t)b * R + idxs[e]) * N_IN + 2*lane);
        a0 += xv.x; a1 += xv.y;
    }
    __shared__ double pp[4][128];
    pp[wave][2*lane]   = a0;
    pp[wave][2*lane+1] = a1;
    __syncthreads();
    if (tid < 128){
        double s = pp[0][tid] + pp[1][tid] + pp[2][tid] + pp[3][tid];
        part[(size_t)(g*64 + m) * N_IN + tid] = s;
    }
}

// ---------------------------------------------------------------------------
// Kernel 8: reduce partials -> virt (/K), then the tiny 2-layer MLP.
// ---------------------------------------------------------------------------
__global__ __launch_bounds__(256) void mlp_kernel(
        const double* __restrict__ part,
        const float* __restrict__ W1, const float* __restrict__ b1,
        const float* __restrict__ W2, const float* __restrict__ b2,
        float* __restrict__ upd)
{
    const int b = blockIdx.x, j = threadIdx.x;
    __shared__ float inv[DD];
    __shared__ float h1[DD];
    {
        const int g = b*2 + (j >> 7);
        const int f = j & 127;
        const double* p = part + (size_t)g * 64 * N_IN + f;
        double s = 0.0;
        for (int m = 0; m < 64; ++m) s += p[(size_t)m * N_IN];
        inv[j] = (float)(s / (double)KSEL);
    }
    __syncthreads();
    double acc = 0.0;
    for (int i = 0; i < DD; ++i) acc += (double)inv[i] * (double)W1[i*DD + j];
    h1[j] = fmaxf((float)(acc + (double)b1[j]), 0.0f);
    __syncthreads();
    acc = 0.0;
    for (int i = 0; i < DD; ++i) acc += (double)h1[i] * (double)W2[i*DD + j];
    upd[b*DD + j] = (float)(acc + (double)b2[j]);
}

// ---------------------------------------------------------------------------
// Kernel 9: final blend.
// ---------------------------------------------------------------------------
__global__ __launch_bounds__(256) void final_kernel(
        const float* __restrict__ x,
        const unsigned char* __restrict__ mask,
        const float* __restrict__ upd,
        float* __restrict__ out, int N, int R)
{
    const int nvec = N * (N_IN / 4);
    const int stride = gridDim.x * blockDim.x;
    for (int idx = blockIdx.x * blockDim.x + threadIdx.x; idx < nvec; idx += stride){
        const int row = idx >> 5;
        const int c = (idx & 31) * 4;
        float4 o = *reinterpret_cast<const float4*>(x + (size_t)row * N_IN + c);
        const int b = row / R;
        const unsigned char m0 = mask[row];
        const unsigned char m1 = mask[(size_t)N + row];
        if (m0){
            const float4 u0 = *reinterpret_cast<const float4*>(upd + b*DD + c);
            o.x = (o.x + u0.x)*0.5f; o.y = (o.y + u0.y)*0.5f;
            o.z = (o.z + u0.z)*0.5f; o.w = (o.w + u0.w)*0.5f;
        }
        if (m1){
            const float4 u1 = *reinterpret_cast<const float4*>(upd + b*DD + 128 + c);
            o.x = (o.x + u1.x)*0.5f; o.y = (o.y + u1.y)*0.5f;
            o.z = (o.z + u1.z)*0.5f; o.w = (o.w + u1.w)*0.5f;
        }
        *reinterpret_cast<float4*>(out + (size_t)row * N_IN + c) = o;
    }
}

extern "C" void kernel_launch(void* const* d_in, const int* in_sizes, int n_in_cnt,
                              void* d_out, int out_size, void* d_ws, size_t ws_size,
                              hipStream_t stream)
{
    const float* x    = (const float*)d_in[0];
    const float* W_fr = (const float*)d_in[1];
    const float* b_fr = (const float*)d_in[2];
    const float* W1   = (const float*)d_in[3];
    const float* b1   = (const float*)d_in[4];
    const float* W2   = (const float*)d_in[5];
    const float* b2   = (const float*)d_in[6];
    float* out = (float*)d_out;

    const int N = in_sizes[0] / N_IN;   // 800000
    const int R = N / NBATCH;           // 100000

    char* ws = (char*)d_ws;
    size_t off = 0;
    auto alloc = [&](size_t bytes) -> void* {
        void* p = ws + off;
        off = (off + bytes + 255) & ~(size_t)255;
        return p;
    };
    unsigned char* mask = (unsigned char*)alloc((size_t)2 * N);
    int*      lists    = (int*)     alloc((size_t)NGROUP * KSEL * 4);
    double*   part     = (double*)  alloc((size_t)NGROUP * 64 * N_IN * 8);
    float*    upd      = (float*)   alloc((size_t)NBATCH * DD * 4);
    unsigned* gParams  = (unsigned*)alloc((size_t)NGROUP * 8 * 4);
    unsigned* gCandCnt = (unsigned*)alloc((size_t)NGROUP * CHUNKS * 4);
    unsigned* gListCnt = (unsigned*)alloc((size_t)NGROUP * 64 * 4);   // padded lines

    // big buffers with d_out-tail fallback (all consumers precede final_kernel)
    const size_t outBytes  = (size_t)out_size * 4;
    char* tail = (char*)d_out + outBytes;
    auto tail_alloc = [&](size_t bytes) -> void* {
        tail -= bytes;
        tail = (char*)((size_t)tail & ~(size_t)255);
        return tail;
    };
    auto big_alloc = [&](size_t bytes) -> void* {
        if (off + bytes <= ws_size) return alloc(bytes);
        return tail_alloc(bytes);
    };
    unsigned* keys  = (unsigned*)big_alloc((size_t)2 * N * 4);
    unsigned* gHist = (unsigned*)big_alloc((size_t)NGROUP * CHUNKS * 2048 * 4);
    int*      cand  = (int*)     big_alloc((size_t)NGROUP * CAND_CAP * 4);

    const int totalWaves = 2048 * 256 / 64;
    scores_kernel<<<dim3(2048), dim3(256), 0, stream>>>(x, W_fr, b_fr, keys, N, totalWaves);
    histA_kernel<<<dim3(NGROUP*CHUNKS), dim3(1024), 0, stream>>>(keys, gHist, N, R);
    threshA_kernel<<<dim3(NGROUP), dim3(256), 0, stream>>>(gHist, gParams);
    collect_kernel<<<dim3(NGROUP*CHUNKS), dim3(1024), 0, stream>>>(keys, gParams, gCandCnt, cand, N, R);
    select2_kernel<<<dim3(NGROUP), dim3(1024), 0, stream>>>(keys, cand, gCandCnt, gParams, gListCnt, N, R);
    write_kernel<<<dim3(NGROUP*WCH), dim3(1024), 0, stream>>>(keys, gParams, mask, lists, gListCnt, N, R);
    virt_partial_kernel<<<dim3(NGROUP*64), dim3(256), 0, stream>>>(x, lists, part, R);
    mlp_kernel<<<dim3(NBATCH), dim3(DD), 0, stream>>>(part, W1, b1, W2, b2, upd);
    final_kernel<<<dim3(2048), dim3(256), 0, stream>>>(x, mask, upd, out, N, R);
}